// Round 7
// baseline (416.011 us; speedup 1.0000x reference)
//
#include <hip/hip_runtime.h>

// Problem constants
#define LROW 32768                   // row length
#define NROW 512                     // rows
#define WIN 100                      // window (34*3-2); 100 = 25 float4s exactly
#define NC (LROW - WIN + 1)          // 32669 output columns
#define NT1 256
#define T 16                         // columns per thread
#define CT (T * NT1)                 // 4096 columns per block
#define NTILE 8                      // ceil(NC/CT)
#define G 4                          // rows per block
#define RG (NROW / G)                // 128 row groups
#define N_TOT (NROW * NC)
#define N4 (N_TOT / 4)
#define RSPLIT 32
#define RCHUNK (NROW / RSPLIT)       // 16 rows per reduce chunk

__device__ __forceinline__ float gc(const float4 v, int c) {
    return c == 0 ? v.x : c == 1 ? v.y : c == 2 ? v.z : v.w;   // static after unroll
}

// Per-(thread,row) window compute: direct global float4 loads, no LDS.
// Thread covers cols [c0, c0+15]; needs elements [c0, c0+114] = vec4s 4t..4t+28.
// GUARD=true only for the last column tile (vec 28 may run off the row end).
template<bool GUARD>
__device__ __forceinline__ void row_compute(
    const float4* __restrict__ q1, const float4* __restrict__ q2,
    float* __restrict__ orow, int c0, int ncols, int vmax)
{
    const float4 z4 = make_float4(0.f, 0.f, 0.f, 0.f);
    float s1 = 0.f, s2 = 0.f, s11 = 0.f, s22 = 0.f, s12 = 0.f;
    float4 ha[4], hb[4], ta[4], tb[4];
    #pragma unroll
    for (int v = 0; v < 4; ++v) { ha[v] = q1[v]; hb[v] = q2[v]; }   // head (subtract side)
    #pragma unroll
    for (int v = 0; v < 4; ++v) {                                   // tail (add side): vecs 25..28
        ta[v] = (!GUARD || (25 + v) <= vmax) ? q1[25 + v] : z4;
        tb[v] = (!GUARD || (25 + v) <= vmax) ? q2[25 + v] : z4;
    }
    // window init: elements 0..99 = vec4s 0..24 (all in-range even when GUARD)
    #pragma unroll
    for (int v = 0; v < 25; ++v) {
        float4 a, b;
        if (v < 4) { a = ha[v]; b = hb[v]; }
        else       { a = q1[v]; b = q2[v]; }
        s1 += a.x; s2 += b.x; s11 = fmaf(a.x, a.x, s11); s22 = fmaf(b.x, b.x, s22); s12 = fmaf(a.x, b.x, s12);
        s1 += a.y; s2 += b.y; s11 = fmaf(a.y, a.y, s11); s22 = fmaf(b.y, b.y, s22); s12 = fmaf(a.y, b.y, s12);
        s1 += a.z; s2 += b.z; s11 = fmaf(a.z, a.z, s11); s22 = fmaf(b.z, b.z, s22); s12 = fmaf(a.z, b.z, s12);
        s1 += a.w; s2 += b.w; s11 = fmaf(a.w, a.w, s11); s22 = fmaf(b.w, b.w, s22); s12 = fmaf(a.w, b.w, s12);
    }
    const float invw = 1.0f / (float)WIN;
    #pragma unroll
    for (int m = 0; m < T; ++m) {
        if (m > 0) {
            const int e = m - 1;                       // compile-time after unroll
            float a_i = gc(ta[e >> 2], e & 3);         // element 100+e
            float b_i = gc(tb[e >> 2], e & 3);
            float a_o = gc(ha[e >> 2], e & 3);         // element e
            float b_o = gc(hb[e >> 2], e & 3);
            s1 += a_i - a_o;
            s2 += b_i - b_o;
            s11 += fmaf(a_i, a_i, -(a_o * a_o));
            s22 += fmaf(b_i, b_i, -(b_o * b_o));
            s12 += fmaf(a_i, b_i, -(a_o * b_o));
        }
        float cov = fmaf(-(s1 * invw), s2, s12);
        float v1v = fmaf(-(s1 * invw), s1, s11);
        float v2v = fmaf(-(s2 * invw), s2, s22);
        float corr = cov * rsqrtf(v1v * v2v);
        if (!GUARD || (c0 + m < ncols)) orow[c0 + m] = corr;
    }
}

// Pass 1: corr for G rows x CT cols per block -> out. No LDS, no barriers.
__global__ __launch_bounds__(NT1, 4)
void swc_pass1(const float* __restrict__ x, float* __restrict__ out)
{
    const int tile = (int)blockIdx.x & (NTILE - 1);
    const int rg   = (int)blockIdx.x >> 3;
    const int j0   = tile * CT;
    const int tid  = (int)threadIdx.x;
    const int c0   = tid * T;
    const bool tailtile = (tile == NTILE - 1);
    const int ncols = tailtile ? (NC - j0) : CT;       // 3997 for tail tile
    if (c0 >= ncols) return;
    // max safe vec index: 16*tid + 4*v + 3 <= (LROW-j0) - 1
    const int vmax = ((LROW - j0 - 4) >> 2) - (tid << 2);

    const int r0 = rg * G;
    for (int rr = 0; rr < G; ++rr) {
        const int r = r0 + rr;
        const float4* __restrict__ q1 =
            (const float4*)(x + ((size_t)(2 * r) + 0) * LROW + j0) + (tid << 2);
        const float4* __restrict__ q2 =
            (const float4*)(x + ((size_t)(2 * r) + 1) * LROW + j0) + (tid << 2);
        float* __restrict__ orow = out + (size_t)r * NC + j0;
        if (tailtile) row_compute<true >(q1, q2, orow, c0, ncols, vmax);
        else          row_compute<false>(q1, q2, orow, c0, ncols, vmax);
    }
}

// Reduce stage 1 (atomic-free): partial[k][col] = sum of rows [16k,16k+16).
__global__ __launch_bounds__(256)
void swc_red1(const float* __restrict__ out, float* __restrict__ partial)
{
    int col = (int)blockIdx.x * 256 + (int)threadIdx.x;
    if (col >= NC) return;
    const int k  = (int)blockIdx.y;
    const int r0 = k * RCHUNK;
    float s = 0.f;
    #pragma unroll
    for (int i = 0; i < RCHUNK; ++i)
        s += out[(size_t)(r0 + i) * NC + col];
    partial[(size_t)k * NC + col] = s;
}

// Reduce stage 2: colsum[col] = sum over 32 partials.
__global__ __launch_bounds__(256)
void swc_red2(const float* __restrict__ partial, float* __restrict__ colsum)
{
    int col = (int)blockIdx.x * 256 + (int)threadIdx.x;
    if (col >= NC) return;
    float s = 0.f;
    #pragma unroll
    for (int k = 0; k < RSPLIT; ++k)
        s += partial[(size_t)k * NC + col];
    colsum[col] = s;
}

// Fallback reduce (small ws): atomicAdd per col per row-chunk.
__global__ __launch_bounds__(256)
void swc_reduce_atomic(const float* __restrict__ out, float* __restrict__ colsum)
{
    int col = (int)blockIdx.x * 256 + (int)threadIdx.x;
    if (col >= NC) return;
    const int r0 = (int)blockIdx.y * RCHUNK;
    float s = 0.f;
    #pragma unroll
    for (int i = 0; i < RCHUNK; ++i)
        s += out[(size_t)(r0 + i) * NC + col];
    atomicAdd(&colsum[col], s);
}

// Pass 2: out = relu(out - colsum/NROW), flat float4 streaming RMW.
__global__ __launch_bounds__(256)
void swc_pass2(float* __restrict__ out, const float* __restrict__ colsum)
{
    const float inv = 1.0f / (float)NROW;
    int base = (int)blockIdx.x * 2048 + (int)threadIdx.x;   // vec4 units
    #pragma unroll
    for (int v = 0; v < 8; ++v) {
        int i4 = base + v * 256;
        if (i4 < N4) {
            float4 o = ((float4*)out)[i4];
            int idx = i4 << 2;
            int row = (int)((unsigned)idx / (unsigned)NC);
            int col = idx - row * NC;                        // avg depends only on col
            int c1 = col + 1, c2 = col + 2, c3 = col + 3;
            if (c1 >= NC) c1 -= NC;
            if (c2 >= NC) c2 -= NC;
            if (c3 >= NC) c3 -= NC;
            o.x = fmaxf(o.x - colsum[col] * inv, 0.f);
            o.y = fmaxf(o.y - colsum[c1] * inv, 0.f);
            o.z = fmaxf(o.z - colsum[c2] * inv, 0.f);
            o.w = fmaxf(o.w - colsum[c3] * inv, 0.f);
            ((float4*)out)[i4] = o;
        }
    }
}

extern "C" void kernel_launch(void* const* d_in, const int* in_sizes, int n_in,
                              void* d_out, int out_size, void* d_ws, size_t ws_size,
                              hipStream_t stream) {
    const float* x = (const float*)d_in[0];
    float* out = (float*)d_out;
    float* colsum = (float*)d_ws;                 // NC floats
    float* partial = colsum + NC;                 // RSPLIT x NC floats
    const size_t need = (size_t)(NC + (size_t)RSPLIT * NC) * sizeof(float);  // ~4.3 MB

    hipMemsetAsync(colsum, 0, NC * sizeof(float), stream);  // needed by atomic path; harmless otherwise
    swc_pass1<<<dim3(NTILE * RG), dim3(NT1), 0, stream>>>(x, out);
    if (ws_size >= need) {   // ws_size is call-invariant -> same launches every call (graph-safe)
        swc_red1<<<dim3((NC + 255) / 256, RSPLIT), dim3(256), 0, stream>>>(out, partial);
        swc_red2<<<dim3((NC + 255) / 256), dim3(256), 0, stream>>>(partial, colsum);
    } else {
        swc_reduce_atomic<<<dim3((NC + 255) / 256, RSPLIT), dim3(256), 0, stream>>>(out, colsum);
    }
    swc_pass2<<<dim3((N4 + 2047) / 2048), dim3(256), 0, stream>>>(out, colsum);
}